// Round 7
// baseline (19.626 us; speedup 1.0000x reference)
//
#include <hip/hip_runtime.h>
#include <hip/hip_bf16.h>

#define NB 16       // batch
#define NS 256      // tokens per row
#define ND 512      // feature dim
#define MAXDUR 10
#define TMAX (NS * MAXDUR)   // 2560
#define ND4 (ND / 4)         // 128 float4 per row
#define TB 32                // t-values per block
#define ITERS (TB * ND4 / 256)  // 16 float4 stores per thread
#define BLOCKS_PER_ROW (TMAX / TB)          // 80
#define NBLK (NB * BLOCKS_PER_ROW)          // 1280 = exactly 5 blocks/CU
#define NXCD 8
#define CHUNK (NBLK / NXCD)                 // 160 blocks per XCD = 2 batch rows

typedef float f32x4 __attribute__((ext_vector_type(4)));

// ---------------------------------------------------------------------------
// Single fused kernel. 1D grid of NBLK blocks, 256 threads.
// Prologue (minimized): each wave independently scans the full 256-duration
// row (int4 load = 4 tokens/lane, in-quad prefix + 6-step shfl scan). All 4
// waves write identical cum values to LDS (benign same-value race) -> no
// cross-wave combine, only 2 barriers total before stores can issue.
// Then binary-search the block's TB frames, and stream TB*ND floats of
// coalesced output.
// out[b,t,:] = (t < mel[b]) ? x[b, idx[b,t], :] : 0 ; mel_out[b] = mel (float)
// ---------------------------------------------------------------------------
__global__ __launch_bounds__(256) void la_fused_kernel(
    const f32x4* __restrict__ x,
    const int* __restrict__ dur,
    f32x4* __restrict__ out,
    float* __restrict__ mel_out) {
    __shared__ int s[NS];
    __shared__ int idx_s[TB];

    // --- XCD-aware block swizzle (bijective: NBLK % NXCD == 0) ---
    const int bid = blockIdx.x;
    const int swz = (bid & (NXCD - 1)) * CHUNK + (bid >> 3);
    const int b   = swz / BLOCKS_PER_ROW;
    const int t0  = (swz - b * BLOCKS_PER_ROW) * TB;

    const int tid  = threadIdx.x;
    const int lane = tid & 63;

    // --- per-wave redundant inclusive scan (no cross-wave dependency) ---
    int4 d = ((const int4*)(dur + b * NS))[lane];   // tokens 4*lane .. 4*lane+3
    int p0 = d.x;
    int p1 = p0 + d.y;
    int p2 = p1 + d.z;
    int p3 = p2 + d.w;                               // in-quad inclusive prefix
    int sc = p3;                                     // quad sum -> shfl scan
    #pragma unroll
    for (int off = 1; off < 64; off <<= 1) {
        int n = __shfl_up(sc, off, 64);
        if (lane >= off) sc += n;
    }
    const int base = sc - p3;                        // exclusive prefix of quads
    ((int4*)s)[lane] = make_int4(base + p0, base + p1, base + p2, base + p3);
    __syncthreads();

    const int mel = s[NS - 1];
    if (t0 == 0 && tid == 0)
        mel_out[b] = (float)mel;    // second tuple output (float32)

    // --- searchsorted for this block's TB frames ---
    if (tid < TB) {
        int t = t0 + tid;
        int lo = 0, hi = NS;
        while (lo < hi) {
            int mid = (lo + hi) >> 1;
            if (s[mid] > t) hi = mid; else lo = mid + 1;
        }
        idx_s[tid] = (lo < NS) ? lo : (NS - 1);
    }
    __syncthreads();

    // --- expand-gather: ITERS coalesced float4 stores per thread ---
    const size_t outbase = ((size_t)b * TMAX + t0) * ND4;
    const size_t xbase   = (size_t)b * NS * ND4;
    #pragma unroll
    for (int k = 0; k < ITERS; ++k) {
        int item = k * 256 + tid;
        int tt   = item >> 7;            // local t in [0, TB)  (wave-uniform)
        int d4   = item & (ND4 - 1);
        f32x4 v = (f32x4)(0.f);
        if (t0 + tt < mel) {
            int src = idx_s[tt];         // LDS broadcast
            v = x[xbase + (size_t)src * ND4 + d4];
        }
        out[outbase + item] = v;
    }
}

extern "C" void kernel_launch(void* const* d_in, const int* in_sizes, int n_in,
                              void* d_out, int out_size, void* d_ws, size_t ws_size,
                              hipStream_t stream) {
    const float* x   = (const float*)d_in[0];
    const int*   dur = (const int*)d_in[1];

    float* out     = (float*)d_out;
    float* mel_out = out + (size_t)NB * TMAX * ND;   // tuple output 1 tail

    la_fused_kernel<<<NBLK, 256, 0, stream>>>(
        (const f32x4*)x, dur, (f32x4*)d_out, mel_out);
}